// Round 18
// baseline (51.019 us; speedup 1.0000x reference)
//
#include <hip/hip_runtime.h>

#define M_ROWS  4096
#define IN_DIM  512
#define NEURONS 1024
#define OUT_DIM 512

typedef _Float16 f16;
typedef __attribute__((ext_vector_type(8))) _Float16 f16x8;
typedef __attribute__((ext_vector_type(4))) _Float16 f16x4;
typedef __attribute__((ext_vector_type(4))) float    f32x4;

// ===========================================================================
// prep:
//  [0,1024)    x f32 -> xh f16
//  [1024,1536) W1 -> W1t [1024][512] f16 (plain)
//  [1536,2048) W2 -> W2t [512][1024] f16, pre-XOR-swizzled kbyte ^= (n&3)<<4
//  [2048,2108) qH[n][ii][4] f16 = power-basis Horner coeffs (spb folded)
// ===========================================================================
__global__ __launch_bounds__(256) void prep(
    const float* __restrict__ x,  f16* __restrict__ xh,
    const float* __restrict__ W1, f16* __restrict__ W1t,
    const float* __restrict__ W2, f16* __restrict__ W2t,
    const float* __restrict__ coeff, const float* __restrict__ spb,
    f16* __restrict__ qH)
{
    __shared__ float S[32][33];
    const int b = blockIdx.x, t = threadIdx.x;
    if (b < 1024) {
        int i = b * 256 + t;
        const float4* p = (const float4*)x;
        float4 a = p[i * 2], c = p[i * 2 + 1];
        f16x8 o = { (f16)a.x, (f16)a.y, (f16)a.z, (f16)a.w,
                    (f16)c.x, (f16)c.y, (f16)c.z, (f16)c.w };
        *(f16x8*)(xh + (size_t)i * 8) = o;
        return;
    }
    if (b < 1536) {                       // W1 transpose -> f16 (plain)
        const int tile = b - 1024;
        const int tx = tile & 31, ty = tile >> 5;
        const int tr = t >> 3, tc = (t & 7) * 4;
        float4 v = *(const float4*)&W1[(size_t)(ty * 32 + tr) * NEURONS + tx * 32 + tc];
        S[tr][tc + 0] = v.x; S[tr][tc + 1] = v.y;
        S[tr][tc + 2] = v.z; S[tr][tc + 3] = v.w;
        __syncthreads();
        f16x4 o = {(f16)S[tc + 0][tr], (f16)S[tc + 1][tr],
                   (f16)S[tc + 2][tr], (f16)S[tc + 3][tr]};
        *(f16x4*)&W1t[(size_t)(tx * 32 + tr) * IN_DIM + ty * 32 + tc] = o;
        return;
    }
    if (b < 2048) {                       // W2 transpose -> f16, swz (n&3)<<4
        const int tile = b - 1536;
        const int nt = tile & 15, kt2 = tile >> 4;
        const int tr = t >> 3, tc = (t & 7) * 4;
        float4 v = *(const float4*)&W2[(size_t)(kt2 * 32 + tr) * OUT_DIM + nt * 32 + tc];
        S[tr][tc + 0] = v.x; S[tr][tc + 1] = v.y;
        S[tr][tc + 2] = v.z; S[tr][tc + 3] = v.w;
        __syncthreads();
        const int n = nt * 32 + tr;
        f16x4 o = {(f16)S[tc + 0][tr], (f16)S[tc + 1][tr],
                   (f16)S[tc + 2][tr], (f16)S[tc + 3][tr]};
        const int kbyte = ((kt2 * 32 + tc) * 2) ^ ((n & 3) << 4);
        *(f16x4*)((char*)W2t + (size_t)n * 2048 + kbyte) = o;
        return;
    }
    {                                     // qH table (f16 power-basis coeffs)
        const int tid = (b - 2048) * 256 + t;
        if (tid < NEURONS * 15) {
            const int n = tid / 15, ii = tid % 15;
            const float s = spb[n];
            const float c0 = coeff[n * 18 + ii]     + s;
            const float c1 = coeff[n * 18 + ii + 1] + s;
            const float c2 = coeff[n * 18 + ii + 2] + s;
            const float c3 = coeff[n * 18 + ii + 3] + s;
            f16x4 q;
            q[0] = (f16)((c0 + 4.0f * c1 + c2) * (1.0f / 6.0f));
            q[1] = (f16)((c2 - c0) * 0.5f);
            q[2] = (f16)((c0 - 2.0f * c1 + c2) * 0.5f);
            q[3] = (f16)((c3 - c0 + 3.0f * (c1 - c2)) * (1.0f / 6.0f));
            *(f16x4*)&qH[(size_t)tid * 4] = q;
        }
    }
}

// ===========================================================================
// gemm1: (verbatim R17) h(f16) = x @ W1 + b1, BM=128 BN=64 BK=64,
// global_load_lds(16B), dbuf, 1 barrier/step; 32 min/max partials per row.
// ===========================================================================
__global__ __launch_bounds__(256) void k_gemm1(
    const f16* __restrict__ A, const f16* __restrict__ Bt,
    const float* __restrict__ b1, f16* __restrict__ h,
    float* __restrict__ pmin, float* __restrict__ pmax)
{
    __shared__ f16 lds[2][(128 + 64) * 64];   // 48 KB

    const int t    = threadIdx.x;
    const int lane = t & 63, l15 = lane & 15, lhi = lane >> 4;
    const int wid  = t >> 6;
    const int wm   = wid >> 1, wn = wid & 1;

    const int flat = blockIdx.y * gridDim.x + blockIdx.x;   // 512 blocks
    const int swz  = (flat & 7) * 64 + (flat >> 3);
    const int m0   = (swz >> 4) * 128;
    const int n0   = (swz & 15) * 64;

    auto stage = [&](int buf, int kt) {
        f16* base = &lds[buf][0];
#pragma unroll
        for (int j = 0; j < 4; ++j) {
            int c = wid * 4 + j;
            const f16* g = A + (size_t)(m0 + c * 8 + (lane >> 3)) * IN_DIM + kt + (lane & 7) * 8;
            __builtin_amdgcn_global_load_lds(
                (const __attribute__((address_space(1))) void*)g,
                (__attribute__((address_space(3))) void*)(base + c * 512), 16, 0, 0);
        }
#pragma unroll
        for (int j = 0; j < 2; ++j) {
            int c = wid * 2 + j;
            const f16* g = Bt + (size_t)(n0 + c * 8 + (lane >> 3)) * IN_DIM + kt + (lane & 7) * 8;
            __builtin_amdgcn_global_load_lds(
                (const __attribute__((address_space(1))) void*)g,
                (__attribute__((address_space(3))) void*)(base + 8192 + c * 512), 16, 0, 0);
        }
    };

    f32x4 acc[4][2];
#pragma unroll
    for (int i = 0; i < 4; ++i)
#pragma unroll
        for (int j = 0; j < 2; ++j) acc[i][j] = (f32x4)0.f;

    stage(0, 0);
    __syncthreads();

    int cur = 0;
    for (int tt = 0; tt < 8; ++tt) {                     // K = 512
        if (tt < 7) stage(cur ^ 1, (tt + 1) * 64);
        const f16* L = &lds[cur][0];
#pragma unroll
        for (int ks = 0; ks < 2; ++ks) {
            f16x8 bfr[2];
#pragma unroll
            for (int nj = 0; nj < 2; ++nj)
                bfr[nj] = *(const f16x8*)
                    &L[8192 + (wn * 32 + nj * 16 + l15) * 64 + ks * 32 + lhi * 8];
#pragma unroll
            for (int mi = 0; mi < 4; ++mi) {
                f16x8 afr = *(const f16x8*)
                    &L[(wm * 64 + mi * 16 + l15) * 64 + ks * 32 + lhi * 8];
#pragma unroll
                for (int nj = 0; nj < 2; ++nj)
                    acc[mi][nj] = __builtin_amdgcn_mfma_f32_16x16x32_f16(
                        afr, bfr[nj], acc[mi][nj], 0, 0, 0);
            }
        }
        __syncthreads();
        cur ^= 1;
    }

    const int nb2 = (n0 >> 6) * 2 + wn;                  // 0..31
#pragma unroll
    for (int mi = 0; mi < 4; ++mi) {
        const int row0 = m0 + wm * 64 + mi * 16 + lhi * 4;
        float vmn[4], vmx[4];
#pragma unroll
        for (int nj = 0; nj < 2; ++nj) {
            const int col = n0 + wn * 32 + nj * 16 + l15;
            const float bv = b1[col];
#pragma unroll
            for (int j = 0; j < 4; ++j) {
                f16 hv = (f16)(acc[mi][nj][j] + bv);
                h[(size_t)(row0 + j) * NEURONS + col] = hv;
                float vr = (float)hv;
                if (nj == 0) { vmn[j] = vr; vmx[j] = vr; }
                else { vmn[j] = fminf(vmn[j], vr); vmx[j] = fmaxf(vmx[j], vr); }
            }
        }
#pragma unroll
        for (int j = 0; j < 4; ++j) {
#pragma unroll
            for (int d = 1; d < 16; d <<= 1) {
                vmn[j] = fminf(vmn[j], __shfl_xor(vmn[j], d));
                vmx[j] = fmaxf(vmx[j], __shfl_xor(vmx[j], d));
            }
        }
        if (l15 == 0) {
#pragma unroll
            for (int j = 0; j < 4; ++j) {
                pmin[(size_t)nb2 * M_ROWS + row0 + j] = vmn[j];
                pmax[(size_t)nb2 * M_ROWS + row0 + j] = vmx[j];
            }
        }
    }
}

// ===========================================================================
// k_spline: sph(f16, pre-swizzled (row&3)<<4) = Horner-spline(norm(h)).
// 1024 blocks x 256 thr; wave per row (4 rows/block); lane covers k=lane*8
// and k=512+lane*8. 32-partial min/max shuffle reduce. qH gathers hit L2 at
// full occupancy (latency hidden by TLP).
// ===========================================================================
__global__ __launch_bounds__(256) void k_spline(
    const f16* __restrict__ h, const float* __restrict__ pmin,
    const float* __restrict__ pmax, const f16* __restrict__ qH,
    f16* __restrict__ sph)
{
    const int t    = threadIdx.x;
    const int lane = t & 63;
    const int row  = blockIdx.x * 4 + (t >> 6);

    float mn = pmin[(size_t)(lane & 31) * M_ROWS + row];
    float mx = pmax[(size_t)(lane & 31) * M_ROWS + row];
#pragma unroll
    for (int d = 1; d < 32; d <<= 1) {
        mn = fminf(mn, __shfl_xor(mn, d));
        mx = fmaxf(mx, __shfl_xor(mx, d));
    }
    const float s15 = 15.0f / (mx - mn + 1e-8f);
    const float o15 = -mn * s15;
    const int   swz = (row & 3) << 4;

#pragma unroll
    for (int half = 0; half < 2; ++half) {
        const int k0 = half * 512 + lane * 8;
        f16x8 hv = *(const f16x8*)&h[(size_t)row * NEURONS + k0];
        f16x8 o;
#pragma unroll
        for (int e = 0; e < 8; ++e) {
            const float t15 = fmaf((float)hv[e], s15, o15);
            float fi = floorf(t15);
            fi = fminf(fmaxf(fi, 0.0f), 14.0f);
            const int   ii = (int)fi;
            const float tl = t15 - fi;
            const f16x4 q  = *(const f16x4*)&qH[((size_t)(k0 + e) * 15 + ii) * 4];
            o[e] = (f16)fmaf(fmaf(fmaf((float)q[3], tl, (float)q[2]),
                                  tl, (float)q[1]),
                             tl, (float)q[0]);
        }
        *(f16x8*)((char*)sph + (size_t)row * 2048 + ((k0 * 2) ^ swz)) = o;
    }
}

// ===========================================================================
// k_gemm2: (R14-proven) out = relu(sph @ W2 + b2). BM=64 BN=64 BK=128,
// 512 blocks (2/CU), 64 KB LDS dbuf, gload_lds(16B), 16 MFMA/step/wave.
// Both operands pre-XOR-swizzled (&3)<<4 in global; XOR on ds_read.
// ===========================================================================
__global__ __launch_bounds__(256) void k_gemm2(
    const f16* __restrict__ A, const f16* __restrict__ Bt,
    const float* __restrict__ b2, float* __restrict__ out)
{
    __shared__ f16 lds[2][128 * 128];                // 64 KB

    const int t    = threadIdx.x;
    const int lane = t & 63, l15 = lane & 15, lhi = lane >> 4;
    const int wid  = t >> 6;
    const int wm   = wid >> 1, wn = wid & 1;

    const int flat = blockIdx.x;                     // 512 blocks
    const int swz  = (flat & 7) * 64 + (flat >> 3);
    const int m0   = (swz >> 3) * 64;                // 64 m-tiles
    const int n0   = (swz & 7) * 64;                 // 8 n-tiles

    auto stage = [&](int buf, int kt) {
        f16* base = &lds[buf][0];
#pragma unroll
        for (int j = 0; j < 4; ++j) {                // A: 16 chunks of 4 rows
            int c = wid * 4 + j;
            const f16* g = A + (size_t)(m0 + c * 4 + (lane >> 4)) * NEURONS + kt + (lane & 15) * 8;
            __builtin_amdgcn_global_load_lds(
                (const __attribute__((address_space(1))) void*)g,
                (__attribute__((address_space(3))) void*)(base + c * 512), 16, 0, 0);
        }
#pragma unroll
        for (int j = 0; j < 4; ++j) {                // B: 16 chunks of 4 rows
            int c = wid * 4 + j;
            const f16* g = Bt + (size_t)(n0 + c * 4 + (lane >> 4)) * NEURONS + kt + (lane & 15) * 8;
            __builtin_amdgcn_global_load_lds(
                (const __attribute__((address_space(1))) void*)g,
                (__attribute__((address_space(3))) void*)(base + 8192 + c * 512), 16, 0, 0);
        }
    };

    f32x4 acc[2][2];
#pragma unroll
    for (int i = 0; i < 2; ++i)
#pragma unroll
        for (int j = 0; j < 2; ++j) acc[i][j] = (f32x4)0.f;

    stage(0, 0);
    __syncthreads();

    const int sA = (l15 & 3) << 4;                   // XOR key (row&3 == l15&3)
    int cur = 0;
    for (int tt = 0; tt < 8; ++tt) {                 // K = 1024, BK = 128
        if (tt < 7) stage(cur ^ 1, (tt + 1) * 128);
        const char* L = (const char*)&lds[cur][0];
#pragma unroll
        for (int ks = 0; ks < 4; ++ks) {
            const int ko = (ks * 64 + lhi * 16) ^ sA;
            f16x8 bfr[2];
#pragma unroll
            for (int nj = 0; nj < 2; ++nj) {
                const int cl = wn * 32 + nj * 16 + l15;
                bfr[nj] = *(const f16x8*)(L + 16384 + (size_t)cl * 256 + ko);
            }
#pragma unroll
            for (int mi = 0; mi < 2; ++mi) {
                const int ar = wm * 32 + mi * 16 + l15;
                f16x8 afr = *(const f16x8*)(L + (size_t)ar * 256 + ko);
#pragma unroll
                for (int nj = 0; nj < 2; ++nj)
                    acc[mi][nj] = __builtin_amdgcn_mfma_f32_16x16x32_f16(
                        afr, bfr[nj], acc[mi][nj], 0, 0, 0);
            }
        }
        __syncthreads();
        cur ^= 1;
    }

    // epilogue: col = l15, row = lhi*4 + j
#pragma unroll
    for (int mi = 0; mi < 2; ++mi) {
        const int row0 = m0 + wm * 32 + mi * 16 + lhi * 4;
#pragma unroll
        for (int nj = 0; nj < 2; ++nj) {
            const int col = n0 + wn * 32 + nj * 16 + l15;
            const float bv = b2[col];
#pragma unroll
            for (int j = 0; j < 4; ++j)
                out[(size_t)(row0 + j) * OUT_DIM + col] =
                    fmaxf(acc[mi][nj][j] + bv, 0.0f);
        }
    }
}

// ===========================================================================
extern "C" void kernel_launch(void* const* d_in, const int* in_sizes, int n_in,
                              void* d_out, int out_size, void* d_ws, size_t ws_size,
                              hipStream_t stream)
{
    const float* x     = (const float*)d_in[0];
    const float* W1    = (const float*)d_in[1];
    const float* b1    = (const float*)d_in[2];
    const float* coeff = (const float*)d_in[3];
    const float* spb   = (const float*)d_in[4];
    const float* W2    = (const float*)d_in[5];
    const float* b2    = (const float*)d_in[6];
    float* out = (float*)d_out;

    char* ws = (char*)d_ws;
    f16*   h    = (f16*)ws;                                   //  8 MB [4096][1024]
    f16*   sph  = (f16*)(ws + ( 8u << 20));                   //  8 MB [4096][1024] swz
    f16*   xh   = (f16*)(ws + (16u << 20));                   //  4 MB [4096][512]
    f16*   W1t  = (f16*)(ws + (20u << 20));                   //  1 MB [1024][512]
    f16*   W2t  = (f16*)(ws + (21u << 20));                   //  1 MB [512][1024] swz
    float* pmin = (float*)(ws + (22u << 20));                 // 512 KB [32][4096]
    float* pmax = (float*)(ws + (22u << 20) + (512u << 10));  // 512 KB
    f16*   qH   = (f16*)(ws + (23u << 20));                   // 120 KB [1024][15][4]

    prep<<<dim3(2108), 256, 0, stream>>>(x, xh, W1, W1t, W2, W2t, coeff, spb, qH);

    k_gemm1<<<dim3(16, 32), 256, 0, stream>>>(xh, W1t, b1, h, pmin, pmax);

    k_spline<<<dim3(1024), 256, 0, stream>>>(h, pmin, pmax, qH, sph);

    k_gemm2<<<dim3(512), 256, 0, stream>>>(sph, W2t, b2, out);
}

// Round 19
// 44.844 us; speedup vs baseline: 1.1377x; 1.1377x over previous
//
#include <hip/hip_runtime.h>

#define M_ROWS  4096
#define IN_DIM  512
#define NEURONS 1024
#define OUT_DIM 512

typedef _Float16 f16;
typedef __attribute__((ext_vector_type(8))) _Float16 f16x8;
typedef __attribute__((ext_vector_type(4))) _Float16 f16x4;
typedef __attribute__((ext_vector_type(4))) float    f32x4;

// ===========================================================================
// prep:
//  [0,1024)    x f32 -> xh f16
//  [1024,1536) W1 -> W1t [1024][512] f16
//  [1536,2048) W2 -> W2t [512][1024] f16, pre-XOR-swizzled kbyte ^= (n&7)<<4
//  [2048,2108) qH[n][ii][4] f16 = POWER-BASIS cubic coeffs of the spline
//              segment (Horner form); spb folds into q0 (partition of unity).
// ===========================================================================
__global__ __launch_bounds__(256) void prep(
    const float* __restrict__ x,  f16* __restrict__ xh,
    const float* __restrict__ W1, f16* __restrict__ W1t,
    const float* __restrict__ W2, f16* __restrict__ W2t,
    const float* __restrict__ coeff, const float* __restrict__ spb,
    f16* __restrict__ qH)
{
    __shared__ float S[32][33];
    const int b = blockIdx.x, t = threadIdx.x;
    if (b < 1024) {
        int i = b * 256 + t;
        const float4* p = (const float4*)x;
        float4 a = p[i * 2], c = p[i * 2 + 1];
        f16x8 o = { (f16)a.x, (f16)a.y, (f16)a.z, (f16)a.w,
                    (f16)c.x, (f16)c.y, (f16)c.z, (f16)c.w };
        *(f16x8*)(xh + (size_t)i * 8) = o;
        return;
    }
    if (b < 1536) {                       // W1 transpose -> f16
        const int tile = b - 1024;
        const int tx = tile & 31, ty = tile >> 5;
        const int tr = t >> 3, tc = (t & 7) * 4;
        float4 v = *(const float4*)&W1[(size_t)(ty * 32 + tr) * NEURONS + tx * 32 + tc];
        S[tr][tc + 0] = v.x; S[tr][tc + 1] = v.y;
        S[tr][tc + 2] = v.z; S[tr][tc + 3] = v.w;
        __syncthreads();
        f16x4 o = {(f16)S[tc + 0][tr], (f16)S[tc + 1][tr],
                   (f16)S[tc + 2][tr], (f16)S[tc + 3][tr]};
        *(f16x4*)&W1t[(size_t)(tx * 32 + tr) * IN_DIM + ty * 32 + tc] = o;
        return;
    }
    if (b < 2048) {                       // W2 transpose -> f16, swizzled
        const int tile = b - 1536;
        const int nt = tile & 15, kt2 = tile >> 4;
        const int tr = t >> 3, tc = (t & 7) * 4;
        float4 v = *(const float4*)&W2[(size_t)(kt2 * 32 + tr) * OUT_DIM + nt * 32 + tc];
        S[tr][tc + 0] = v.x; S[tr][tc + 1] = v.y;
        S[tr][tc + 2] = v.z; S[tr][tc + 3] = v.w;
        __syncthreads();
        const int n = nt * 32 + tr;
        f16x4 o = {(f16)S[tc + 0][tr], (f16)S[tc + 1][tr],
                   (f16)S[tc + 2][tr], (f16)S[tc + 3][tr]};
        const int kbyte = ((kt2 * 32 + tc) * 2) ^ ((n & 7) << 4);
        *(f16x4*)((char*)W2t + (size_t)n * 2048 + kbyte) = o;
        return;
    }
    {                                     // qH table (f16 power-basis coeffs)
        const int tid = (b - 2048) * 256 + t;
        if (tid < NEURONS * 15) {
            const int n = tid / 15, ii = tid % 15;
            const float s = spb[n];
            const float c0 = coeff[n * 18 + ii]     + s;
            const float c1 = coeff[n * 18 + ii + 1] + s;
            const float c2 = coeff[n * 18 + ii + 2] + s;
            const float c3 = coeff[n * 18 + ii + 3] + s;
            f16x4 q;
            q[0] = (f16)((c0 + 4.0f * c1 + c2) * (1.0f / 6.0f));
            q[1] = (f16)((c2 - c0) * 0.5f);
            q[2] = (f16)((c0 - 2.0f * c1 + c2) * 0.5f);
            q[3] = (f16)((c3 - c0 + 3.0f * (c1 - c2)) * (1.0f / 6.0f));
            *(f16x4*)&qH[(size_t)tid * 4] = q;
        }
    }
}

// ===========================================================================
// gemm1: h(f16) = x @ W1 + b1, BM=128 BN=64 BK=64, global_load_lds(16B),
// dbuf, 1 barrier/step; 32 min/max partials per row (no atomics/init).
// ===========================================================================
__global__ __launch_bounds__(256) void k_gemm1(
    const f16* __restrict__ A, const f16* __restrict__ Bt,
    const float* __restrict__ b1, f16* __restrict__ h,
    float* __restrict__ pmin, float* __restrict__ pmax)
{
    __shared__ f16 lds[2][(128 + 64) * 64];   // 48 KB

    const int t    = threadIdx.x;
    const int lane = t & 63, l15 = lane & 15, lhi = lane >> 4;
    const int wid  = t >> 6;
    const int wm   = wid >> 1, wn = wid & 1;

    const int flat = blockIdx.y * gridDim.x + blockIdx.x;   // 512 blocks
    const int swz  = (flat & 7) * 64 + (flat >> 3);
    const int m0   = (swz >> 4) * 128;
    const int n0   = (swz & 15) * 64;

    auto stage = [&](int buf, int kt) {
        f16* base = &lds[buf][0];
#pragma unroll
        for (int j = 0; j < 4; ++j) {
            int c = wid * 4 + j;
            const f16* g = A + (size_t)(m0 + c * 8 + (lane >> 3)) * IN_DIM + kt + (lane & 7) * 8;
            __builtin_amdgcn_global_load_lds(
                (const __attribute__((address_space(1))) void*)g,
                (__attribute__((address_space(3))) void*)(base + c * 512), 16, 0, 0);
        }
#pragma unroll
        for (int j = 0; j < 2; ++j) {
            int c = wid * 2 + j;
            const f16* g = Bt + (size_t)(n0 + c * 8 + (lane >> 3)) * IN_DIM + kt + (lane & 7) * 8;
            __builtin_amdgcn_global_load_lds(
                (const __attribute__((address_space(1))) void*)g,
                (__attribute__((address_space(3))) void*)(base + 8192 + c * 512), 16, 0, 0);
        }
    };

    f32x4 acc[4][2];
#pragma unroll
    for (int i = 0; i < 4; ++i)
#pragma unroll
        for (int j = 0; j < 2; ++j) acc[i][j] = (f32x4)0.f;

    stage(0, 0);
    __syncthreads();

    int cur = 0;
    for (int tt = 0; tt < 8; ++tt) {                     // K = 512
        if (tt < 7) stage(cur ^ 1, (tt + 1) * 64);
        const f16* L = &lds[cur][0];
#pragma unroll
        for (int ks = 0; ks < 2; ++ks) {
            f16x8 bfr[2];
#pragma unroll
            for (int nj = 0; nj < 2; ++nj)
                bfr[nj] = *(const f16x8*)
                    &L[8192 + (wn * 32 + nj * 16 + l15) * 64 + ks * 32 + lhi * 8];
#pragma unroll
            for (int mi = 0; mi < 4; ++mi) {
                f16x8 afr = *(const f16x8*)
                    &L[(wm * 64 + mi * 16 + l15) * 64 + ks * 32 + lhi * 8];
#pragma unroll
                for (int nj = 0; nj < 2; ++nj)
                    acc[mi][nj] = __builtin_amdgcn_mfma_f32_16x16x32_f16(
                        afr, bfr[nj], acc[mi][nj], 0, 0, 0);
            }
        }
        __syncthreads();
        cur ^= 1;
    }

    const int nb2 = (n0 >> 6) * 2 + wn;                  // 0..31
#pragma unroll
    for (int mi = 0; mi < 4; ++mi) {
        const int row0 = m0 + wm * 64 + mi * 16 + lhi * 4;
        float vmn[4], vmx[4];
#pragma unroll
        for (int nj = 0; nj < 2; ++nj) {
            const int col = n0 + wn * 32 + nj * 16 + l15;
            const float bv = b1[col];
#pragma unroll
            for (int j = 0; j < 4; ++j) {
                f16 hv = (f16)(acc[mi][nj][j] + bv);
                h[(size_t)(row0 + j) * NEURONS + col] = hv;
                float vr = (float)hv;
                if (nj == 0) { vmn[j] = vr; vmx[j] = vr; }
                else { vmn[j] = fminf(vmn[j], vr); vmx[j] = fmaxf(vmx[j], vr); }
            }
        }
#pragma unroll
        for (int j = 0; j < 4; ++j) {
#pragma unroll
            for (int d = 1; d < 16; d <<= 1) {
                vmn[j] = fminf(vmn[j], __shfl_xor(vmn[j], d));
                vmx[j] = fmaxf(vmx[j], __shfl_xor(vmx[j], d));
            }
        }
        if (l15 == 0) {
#pragma unroll
            for (int j = 0; j < 4; ++j) {
                pmin[(size_t)nb2 * M_ROWS + row0 + j] = vmn[j];
                pmax[(size_t)nb2 * M_ROWS + row0 + j] = vmx[j];
            }
        }
    }
}

// ===========================================================================
// sp_gemm2: out = relu(spline(norm(h)) @ W2 + b2), fused. BM=32, BN=128,
// BK=64, 512 blocks (2/CU), all buffers double. Spline = power-basis Horner
// (t15 fma + clamp + 1 LDS gather + 3 FMA). B via global_load_lds from
// pre-swizzled W2t, XOR on ds_read. qH slices staged 2 steps ahead.
// ===========================================================================
__global__ __launch_bounds__(256) void sp_gemm2(
    const f16* __restrict__ h, const float* __restrict__ pmin,
    const float* __restrict__ pmax, const f16* __restrict__ qH,
    const f16* __restrict__ W2t, const float* __restrict__ b2,
    float* __restrict__ out)
{
    __shared__ __align__(16) f16 Bb[2][128 * 64];        // 32 KB
    __shared__ __align__(16) f16 Aa[2][32 * 72];         // 9 KB (padded)
    __shared__ __align__(16) f16 cpS[2][4096];           // 16 KB
    __shared__ float sS[32], oS[32];

    const int t    = threadIdx.x;
    const int lane = t & 63, l15 = lane & 15, lhi = lane >> 4;
    const int wid  = t >> 6;
    const int wm   = wid & 1, wn = wid >> 1;

    const int flat = blockIdx.x;
    const int swz  = (flat & 7) * 64 + (flat >> 3);
    const int m0   = (swz & 127) * 32;
    const int n0   = (swz >> 7) * 128;

    auto stageB = [&](int s) {
        f16* base = &Bb[s & 1][0];
#pragma unroll
        for (int j = 0; j < 4; ++j) {
            const int c = wid * 4 + j;                   // 16 chunks of 8 rows
            const char* src = (const char*)W2t + (size_t)(n0 + c * 8 + (lane >> 3)) * 2048
                              + s * 128 + (lane & 7) * 16;
            __builtin_amdgcn_global_load_lds(
                (const __attribute__((address_space(1))) void*)src,
                (__attribute__((address_space(3))) void*)((char*)base + c * 1024),
                16, 0, 0);
        }
    };
    auto stageCp = [&](int s) {
        const char* src = (const char*)qH + (size_t)s * 7680 + (wid * 64 + lane) * 16;
        char* base = (char*)&cpS[s & 1][0];
        __builtin_amdgcn_global_load_lds(
            (const __attribute__((address_space(1))) void*)src,
            (__attribute__((address_space(3))) void*)(base + wid * 1024), 16, 0, 0);
        __builtin_amdgcn_global_load_lds(
            (const __attribute__((address_space(1))) void*)(src + 4096),
            (__attribute__((address_space(3))) void*)(base + 4096 + wid * 1024), 16, 0, 0);
    };

    const int sr_ = t >> 3;                              // spline row 0..31
    const int sk8 = (t & 7) * 8;                         // k-offset 0..56
    auto splineA = [&](int s) {
        const float s15 = sS[sr_], o15 = oS[sr_];
        const f16* cps = &cpS[s & 1][0];
        f16x8 hv = *(const f16x8*)&h[(size_t)(m0 + sr_) * NEURONS + s * 64 + sk8];
        f16x8 o;
#pragma unroll
        for (int e = 0; e < 8; ++e) {
            const float t15 = fmaf((float)hv[e], s15, o15);
            float fi = floorf(t15);
            fi = fminf(fmaxf(fi, 0.0f), 14.0f);          // med3 clamp
            const int   ii = (int)fi;
            const float tl = t15 - fi;
            const f16x4 q  = *(const f16x4*)&cps[((sk8 + e) * 15 + ii) * 4];
            const float r  = fmaf(fmaf(fmaf((float)q[3], tl, (float)q[2]),
                                       tl, (float)q[1]),
                                  tl, (float)q[0]);
            o[e] = (f16)r;
        }
        *(f16x8*)&Aa[s & 1][sr_ * 72 + sk8] = o;
    };

    // ---- prologue --------------------------------------------------------
    stageCp(0); stageCp(1); stageB(0);
    if (t < 32) {
        const int row = m0 + t;
        float a = pmin[row], b = pmax[row];
#pragma unroll
        for (int p = 1; p < 32; ++p) {
            a = fminf(a, pmin[(size_t)p * M_ROWS + row]);
            b = fmaxf(b, pmax[(size_t)p * M_ROWS + row]);
        }
        const float s15 = 15.0f / (b - a + 1e-8f);
        sS[t] = s15;
        oS[t] = -a * s15;
    }
    __syncthreads();          // DMAs drained; sS/oS visible
    splineA(0);
    __syncthreads();          // Aa[0] visible

    f32x4 acc[4];
#pragma unroll
    for (int j = 0; j < 4; ++j) acc[j] = (f32x4)0.f;

    for (int s = 0; s < 16; ++s) {                       // K = 1024
        if (s + 1 < 16) {
            stageB(s + 1);
            if (s + 2 < 16) stageCp(s + 2);
            splineA(s + 1);                              // cpS[(s+1)&1] resident
        }
        const char* B_ = (const char*)&Bb[s & 1][0];
        const f16*  A_ = &Aa[s & 1][0];
#pragma unroll
        for (int ks = 0; ks < 2; ++ks) {
            f16x8 afr = *(const f16x8*)&A_[(wm * 16 + l15) * 72 + ks * 32 + lhi * 8];
#pragma unroll
            for (int nj = 0; nj < 4; ++nj) {
                const int cl = wn * 64 + nj * 16 + l15;
                const int kb = (ks * 64 + lhi * 16) ^ ((cl & 7) << 4);
                f16x8 bfr = *(const f16x8*)(B_ + (size_t)cl * 128 + kb);
                acc[nj] = __builtin_amdgcn_mfma_f32_16x16x32_f16(afr, bfr, acc[nj], 0, 0, 0);
            }
        }
        __syncthreads();
    }

    // epilogue: col = l15, row = lhi*4 + j
    const int row0 = m0 + wm * 16 + lhi * 4;
#pragma unroll
    for (int nj = 0; nj < 4; ++nj) {
        const int col = n0 + wn * 64 + nj * 16 + l15;
        const float bv = b2[col];
#pragma unroll
        for (int j = 0; j < 4; ++j)
            out[(size_t)(row0 + j) * OUT_DIM + col] =
                fmaxf(acc[nj][j] + bv, 0.0f);
    }
}

// ===========================================================================
extern "C" void kernel_launch(void* const* d_in, const int* in_sizes, int n_in,
                              void* d_out, int out_size, void* d_ws, size_t ws_size,
                              hipStream_t stream)
{
    const float* x     = (const float*)d_in[0];
    const float* W1    = (const float*)d_in[1];
    const float* b1    = (const float*)d_in[2];
    const float* coeff = (const float*)d_in[3];
    const float* spb   = (const float*)d_in[4];
    const float* W2    = (const float*)d_in[5];
    const float* b2    = (const float*)d_in[6];
    float* out = (float*)d_out;

    char* ws = (char*)d_ws;
    f16*   h    = (f16*)ws;                                   //  8 MB [4096][1024]
    f16*   xh   = (f16*)(ws + ( 8u << 20));                   //  4 MB [4096][512]
    f16*   W1t  = (f16*)(ws + (12u << 20));                   //  1 MB [1024][512]
    f16*   W2t  = (f16*)(ws + (13u << 20));                   //  1 MB [512][1024] swz
    float* pmin = (float*)(ws + (14u << 20));                 // 512 KB [32][4096]
    float* pmax = (float*)(ws + (14u << 20) + (512u << 10));  // 512 KB
    f16*   qH   = (f16*)(ws + (15u << 20));                   // 120 KB [1024][15][4]

    prep<<<dim3(2108), 256, 0, stream>>>(x, xh, W1, W1t, W2, W2t, coeff, spb, qH);

    k_gemm1<<<dim3(16, 32), 256, 0, stream>>>(xh, W1t, b1, h, pmin, pmax);

    sp_gemm2<<<dim3(512), 256, 0, stream>>>(h, pmin, pmax, qH, W2t, b2, out);
}